// Round 4
// baseline (2107.282 us; speedup 1.0000x reference)
//
#include <hip/hip_runtime.h>
#include <hip/hip_bf16.h>
#include <stdint.h>

// CustomLSTMForecast: B=512, T=256, I=256, H=512
// Persistent-weight LSTM (R2 skeleton + contention-free flag sync):
//   grid = 256 WGs (8 batch-chunks x 32 col-groups, chunk = wg&7), block =
//   256 (4 waves). WG owns batch rows [chunk*64,+64), h-cols [jb*16,+16).
//   ALL weights (96 KiB bf16) LDS-resident (1 WG/CU). h exchanged via L3
//   (sc0 sc1 bypass loads/stores) — placement-independent, no fences, L2
//   never invalidated. Sync = per-(chunk,wave,jb) monotonic flag WORDS
//   (plain stores, no atomic RMW) + 32-lane coalesced spin.
//   x-part GEMM for t+1 runs post-publish into a 2nd accumulator set.

#define B_SZ 512
#define T_SZ 256
#define I_SZ 256
#define H_SZ 512
#define K_SZ 768           // H + I
#define BH   (B_SZ * H_SZ)

typedef float  f32x4  __attribute__((ext_vector_type(4)));
typedef __bf16 bf16x8 __attribute__((ext_vector_type(8)));

__device__ __forceinline__ float fast_sigmoid(float v) {
  return __builtin_amdgcn_rcpf(1.0f + __expf(-v));
}
__device__ __forceinline__ float fast_tanh(float v) {
  return 1.0f - 2.0f * __builtin_amdgcn_rcpf(1.0f + __expf(2.0f * v));
}

// L3-coherent 16B load: dst <- [hsrc + imm], bypass L1+L2
#define HLOAD(dst, off) \
  asm volatile("global_load_dwordx4 %0, %1, off offset:" off " sc0 sc1" \
               : "=v"(dst) : "v"(hsrc) : "memory")
// L3-coherent 2B store: [hdst + imm] <- low16(val)
#define HSTORE(off, val) \
  asm volatile("global_store_short %0, %1, off offset:" off " sc0 sc1" \
               :: "v"(hdst), "v"(val) : "memory")

__global__ __launch_bounds__(256, 1)
void lstm_persist(const float* __restrict__ x,
                  const float* __restrict__ Ww,
                  const float* __restrict__ Wb,
                  __bf16* __restrict__ hbuf,        // 2 * B * H bf16 (dbuf)
                  float* __restrict__ hf32,         // B * H final h (f32)
                  unsigned int* __restrict__ flags) // [8 chunk][4 wv][32 jb]
{
  // B-fragments for ALL weights: c = kt*4 + nt; kt<16 = h-part (k=kt*32),
  // kt>=16 = x-part (k>=512).
  __shared__ bf16x8 bw[96 * 64];  // 96 KiB (forces 1 WG/CU)

  const int wg    = blockIdx.x;
  const int chunk = wg & 7;   // batch chunk of 64 rows (XCD-affine RR)
  const int jb    = wg >> 3;  // h-col group of 16, 0..31
  const int tid   = threadIdx.x;
  const int wv    = tid >> 6; // wave = m-tile (16 batch rows)
  const int ln    = tid & 63;
  const int l16   = ln & 15;
  const int lhi   = ln >> 4;  // 0..3

  const int colW = jb * 16 + l16;  // this lane's h-column

  // ---- stage all weight fragments into LDS ----
  for (int c = wv; c < 96; c += 4) {
    const int kt = c >> 2;
    const int nt = c & 3;
    const int k0 = kt * 32 + lhi * 8;
    const float* wr = Ww + (size_t)(nt * 512 + colW) * K_SZ + k0;
    const float4 w0 = *(const float4*)(wr);
    const float4 w1 = *(const float4*)(wr + 4);
    bf16x8 v;
    v[0]=(__bf16)w0.x; v[1]=(__bf16)w0.y; v[2]=(__bf16)w0.z; v[3]=(__bf16)w0.w;
    v[4]=(__bf16)w1.x; v[5]=(__bf16)w1.y; v[6]=(__bf16)w1.z; v[7]=(__bf16)w1.w;
    bw[c * 64 + ln] = v;
  }

  const float bias0 = Wb[0 * 512 + colW];
  const float bias1 = Wb[1 * 512 + colW];
  const float bias2 = Wb[2 * 512 + colW];
  const float bias3 = Wb[3 * 512 + colW];

  __syncthreads();  // weights ready (only barrier in the kernel)

  const int rowA = chunk * 64 + wv * 16 + l16;      // A-fragment row
  const int rowD = chunk * 64 + wv * 16 + lhi * 4;  // D rows base (+r)
  const float* xlane = x + (size_t)rowA * T_SZ * I_SZ + lhi * 8;
  unsigned int* fbase = flags + (chunk * 4 + wv) * 32;
  const unsigned int* fspin = fbase + (ln & 31);
  unsigned int* fq = fbase + jb;      // this wave's flag word (ln==0 stores)
  __bf16* hb0 = hbuf;
  __bf16* hb1 = hbuf + BH;

  float cst[4] = {0.f, 0.f, 0.f, 0.f};

  // x-part GEMM for step tn into accN (B frags from LDS)
  auto xpart = [&](f32x4 (&accN)[4], int tn) {
#pragma unroll
    for (int nt = 0; nt < 4; ++nt) accN[nt] = (f32x4){0.f, 0.f, 0.f, 0.f};
    const float* xr = xlane + (size_t)tn * I_SZ;
#pragma unroll
    for (int q = 0; q < 8; ++q) {
      const float4 a0 = *(const float4*)(xr + q * 32);
      const float4 a1 = *(const float4*)(xr + q * 32 + 4);
      bf16x8 a;
      a[0]=(__bf16)a0.x; a[1]=(__bf16)a0.y; a[2]=(__bf16)a0.z; a[3]=(__bf16)a0.w;
      a[4]=(__bf16)a1.x; a[5]=(__bf16)a1.y; a[6]=(__bf16)a1.z; a[7]=(__bf16)a1.w;
#pragma unroll
      for (int nt = 0; nt < 4; ++nt)
        accN[nt] = __builtin_amdgcn_mfma_f32_16x16x32_bf16(
                     a, bw[((16 + q) * 4 + nt) * 64 + ln], accN[nt], 0, 0, 0);
    }
  };

  // one timestep: consumes acc (pre-seeded with x-part of t), then
  // computes accN = x-part of t+1 after publishing h_{t+1}
  auto step = [&](f32x4 (&acc)[4], f32x4 (&accN)[4], int t) {
    if (t > 0) {
      // spin until all 32 col-groups published h_t (coalesced flag line)
      unsigned fv;
      do {
        asm volatile("global_load_dword %0, %1, off sc0 sc1\n\t"
                     "s_waitcnt vmcnt(0)"
                     : "=v"(fv) : "v"(fspin) : "memory");
      } while (__any((int)(fv < (unsigned)t)));

      const __bf16* hsrc = ((t & 1) ? hb1 : hb0)
                           + (size_t)rowA * H_SZ + lhi * 8;
      bf16x8 hf[16];
      HLOAD(hf[0],  "0");   HLOAD(hf[1],  "64");  HLOAD(hf[2],  "128");
      HLOAD(hf[3],  "192"); HLOAD(hf[4],  "256"); HLOAD(hf[5],  "320");
      HLOAD(hf[6],  "384"); HLOAD(hf[7],  "448"); HLOAD(hf[8],  "512");
      HLOAD(hf[9],  "576"); HLOAD(hf[10], "640"); HLOAD(hf[11], "704");
      HLOAD(hf[12], "768"); HLOAD(hf[13], "832"); HLOAD(hf[14], "896");
      HLOAD(hf[15], "960");
      asm volatile("s_waitcnt vmcnt(0)" ::: "memory");
      __builtin_amdgcn_sched_barrier(0);
#pragma unroll
      for (int kt = 0; kt < 16; ++kt) {
#pragma unroll
        for (int nt = 0; nt < 4; ++nt)
          acc[nt] = __builtin_amdgcn_mfma_f32_16x16x32_bf16(
                      hf[kt], bw[(kt * 4 + nt) * 64 + ln], acc[nt], 0, 0, 0);
      }
    }

    // elementwise LSTM: acc[0..3][r] = f/i/o/chat for the SAME (row,col)
    float hnv[4];
#pragma unroll
    for (int r = 0; r < 4; ++r) {
      const float fg = fast_sigmoid(acc[0][r] + bias0);
      const float ig = fast_sigmoid(acc[1][r] + bias1);
      const float og = fast_sigmoid(acc[2][r] + bias2);
      const float gg = fast_tanh(acc[3][r] + bias3);
      const float cn = fg * cst[r] + ig * gg;
      cst[r] = cn;
      hnv[r] = og * fast_tanh(cn);
    }

    if (t < T_SZ - 1) {
      // publish h_{t+1} to L3, then set this wave's flag word (no RMW)
      __bf16* hdst = ((t & 1) ? hb0 : hb1) + (size_t)rowD * H_SZ + colW;
      const unsigned u0 = __builtin_bit_cast(unsigned short, (__bf16)hnv[0]);
      const unsigned u1 = __builtin_bit_cast(unsigned short, (__bf16)hnv[1]);
      const unsigned u2 = __builtin_bit_cast(unsigned short, (__bf16)hnv[2]);
      const unsigned u3 = __builtin_bit_cast(unsigned short, (__bf16)hnv[3]);
      HSTORE("0",    u0);
      HSTORE("1024", u1);
      HSTORE("2048", u2);
      HSTORE("3072", u3);
      asm volatile("s_waitcnt vmcnt(0)" ::: "memory");  // h at L3
      if (ln == 0) {
        const unsigned tv = (unsigned)(t + 1);
        asm volatile("global_store_dword %0, %1, off sc0 sc1"
                     :: "v"(fq), "v"(tv) : "memory");
      }
      // x-part for t+1 (overlaps other WGs' publish + flag propagation)
      xpart(accN, t + 1);
    } else {
      // final h -> f32 for the fc head (plain stores; kernel-end release)
#pragma unroll
      for (int r = 0; r < 4; ++r)
        hf32[(size_t)(rowD + r) * H_SZ + colW] = hnv[r];
    }
  };

  f32x4 accA[4], accB[4];
  xpart(accA, 0);                    // seed t=0 (h0 = 0 => no h-part)
  for (int t2 = 0; t2 < T_SZ; t2 += 2) {
    step(accA, accB, t2);
    step(accB, accA, t2 + 1);
  }
}

// out[b] = dot(h_T[b], fc_w) + fc_b
__global__ __launch_bounds__(256)
void fc_head(const float* __restrict__ hf32, const float* __restrict__ fcw,
             const float* __restrict__ fcb, float* __restrict__ out)
{
  const int b = blockIdx.x * 256 + threadIdx.x;
  if (b >= B_SZ) return;
  const float4* hp = (const float4*)(hf32 + (size_t)b * H_SZ);
  const float4* wp = (const float4*)fcw;
  float s = 0.f;
#pragma unroll 8
  for (int j = 0; j < H_SZ / 4; ++j) {
    const float4 h = hp[j];
    const float4 w = wp[j];
    s += h.x * w.x + h.y * w.y + h.z * w.z + h.w * w.w;
  }
  out[b] = s + fcb[0];
}

extern "C" void kernel_launch(void* const* d_in, const int* in_sizes, int n_in,
                              void* d_out, int out_size, void* d_ws, size_t ws_size,
                              hipStream_t stream) {
  const float* x   = (const float*)d_in[0];  // (B, T, I) f32
  const float* Ww  = (const float*)d_in[1];  // (2048, 768) f32
  const float* Wb  = (const float*)d_in[2];  // (2048,) f32
  const float* fcw = (const float*)d_in[3];  // (1, 512) f32
  const float* fcb = (const float*)d_in[4];  // (1,) f32
  float* out = (float*)d_out;                // (B, 1) f32

  char* ws = (char*)d_ws;
  // layout: [flags 4KiB][h0 512KiB][h1 512KiB][hf32 1MiB]
  unsigned int* flags = (unsigned int*)ws;
  __bf16* hbuf = (__bf16*)(ws + 4096);
  float*  hf32 = (float*)(ws + 4096 + (size_t)2 * BH * sizeof(__bf16));

  // zero the flag words only (h0 never read: h-part skipped at t=0)
  hipMemsetAsync(ws, 0, 4096, stream);

  lstm_persist<<<256, 256, 0, stream>>>(x, Ww, Wb, hbuf, hf32, flags);
  fc_head<<<2, 256, 0, stream>>>(hf32, fcw, fcb, out);
}

// Round 5
// 1781.205 us; speedup vs baseline: 1.1831x; 1.1831x over previous
//
#include <hip/hip_runtime.h>
#include <hip/hip_bf16.h>
#include <stdint.h>

// CustomLSTMForecast: B=512, T=256, I=256, H=512
// Persistent-weight LSTM. Grid = 256 WGs (8 chunks x 32 col-groups,
// chunk = wg&7 -> XCD-affine), block = 256 (4 waves), 1 WG/CU (96 KiB LDS).
// ALL weights LDS-resident as MFMA B-fragments.
// h exchange (FAST path): FRESH buffer per timestep (255 x 0.5 MB in d_ws).
//   Producer: sc0 sc1 write-through stores -> vmcnt(0) -> sc1 flag store.
//   Consumer: sc1 flag spin -> PLAIN CACHED loads (fresh address => L2 miss
//   => fetch from L3 which holds the data; chunk-mates then hit L2).
//   => kills the 32x uncached read amplification that dominated R2/R4.
// FALLBACK (small ws): 2 rotating buffers, sc1 reads (R4 scheme).

#define B_SZ 512
#define T_SZ 256
#define I_SZ 256
#define H_SZ 512
#define K_SZ 768           // H + I
#define BH   (B_SZ * H_SZ)

typedef float  f32x4  __attribute__((ext_vector_type(4)));
typedef __bf16 bf16x8 __attribute__((ext_vector_type(8)));

__device__ __forceinline__ float fast_sigmoid(float v) {
  return __builtin_amdgcn_rcpf(1.0f + __expf(-v));
}
__device__ __forceinline__ float fast_tanh(float v) {
  return 1.0f - 2.0f * __builtin_amdgcn_rcpf(1.0f + __expf(2.0f * v));
}

// L3-coherent 16B load (bypass L1+L2): dst <- [hsrc + imm]
#define HLOAD(dst, off) \
  asm volatile("global_load_dwordx4 %0, %1, off offset:" off " sc0 sc1" \
               : "=v"(dst) : "v"(hsrc) : "memory")
// L3-coherent 2B store: [hdst + imm] <- low16(val)
#define HSTORE(off, val) \
  asm volatile("global_store_short %0, %1, off offset:" off " sc0 sc1" \
               :: "v"(hdst), "v"(val) : "memory")

template <bool FAST>
__global__ __launch_bounds__(256, 1)
void lstm_persist(const float* __restrict__ x,
                  const float* __restrict__ Ww,
                  const float* __restrict__ Wb,
                  __bf16* __restrict__ hbase,       // FAST: 255*BH, else 2*BH
                  float* __restrict__ hf32,         // B * H final h (f32)
                  unsigned int* __restrict__ flags) // [8 chunk][4 wv][32 jb]
{
  // B-fragments for ALL weights: c = kt*4 + nt; kt<16 = h-part (k=kt*32),
  // kt>=16 = x-part (k>=512).
  __shared__ bf16x8 bw[96 * 64];  // 96 KiB (forces 1 WG/CU)

  const int wg    = blockIdx.x;
  const int chunk = wg & 7;   // batch chunk of 64 rows (XCD-affine RR)
  const int jb    = wg >> 3;  // h-col group of 16, 0..31
  const int tid   = threadIdx.x;
  const int wv    = tid >> 6; // wave = m-tile (16 batch rows)
  const int ln    = tid & 63;
  const int l16   = ln & 15;
  const int lhi   = ln >> 4;  // 0..3

  const int colW = jb * 16 + l16;  // this lane's h-column

  // ---- stage all weight fragments into LDS ----
  for (int c = wv; c < 96; c += 4) {
    const int kt = c >> 2;
    const int nt = c & 3;
    const int k0 = kt * 32 + lhi * 8;
    const float* wr = Ww + (size_t)(nt * 512 + colW) * K_SZ + k0;
    const float4 w0 = *(const float4*)(wr);
    const float4 w1 = *(const float4*)(wr + 4);
    bf16x8 v;
    v[0]=(__bf16)w0.x; v[1]=(__bf16)w0.y; v[2]=(__bf16)w0.z; v[3]=(__bf16)w0.w;
    v[4]=(__bf16)w1.x; v[5]=(__bf16)w1.y; v[6]=(__bf16)w1.z; v[7]=(__bf16)w1.w;
    bw[c * 64 + ln] = v;
  }

  const float bias0 = Wb[0 * 512 + colW];
  const float bias1 = Wb[1 * 512 + colW];
  const float bias2 = Wb[2 * 512 + colW];
  const float bias3 = Wb[3 * 512 + colW];

  __syncthreads();  // weights ready (only barrier in the kernel)

  const int rowA = chunk * 64 + wv * 16 + l16;      // A-fragment row
  const int rowD = chunk * 64 + wv * 16 + lhi * 4;  // D rows base (+r)
  const float* xlane = x + (size_t)rowA * T_SZ * I_SZ + lhi * 8;
  unsigned int* fbase = flags + (chunk * 4 + wv) * 32;
  const unsigned int* fspin = fbase + (ln & 31);
  unsigned int* fq = fbase + jb;      // this wave's flag word (ln==0 stores)

  float cst[4] = {0.f, 0.f, 0.f, 0.f};

  // x prefetch registers: hold x(t+1) f32, converted at consume time
  float4 xp0[8], xp1[8];
  auto xprefetch = [&](int tn) {
    if (tn >= T_SZ) return;
    const float* xr = xlane + (size_t)tn * I_SZ;
#pragma unroll
    for (int q = 0; q < 8; ++q) {
      xp0[q] = *(const float4*)(xr + q * 32);
      xp1[q] = *(const float4*)(xr + q * 32 + 4);
    }
  };

  // x-part GEMM consuming the prefetch regs into accN
  auto xpart = [&](f32x4 (&accN)[4]) {
#pragma unroll
    for (int nt = 0; nt < 4; ++nt) accN[nt] = (f32x4){0.f, 0.f, 0.f, 0.f};
#pragma unroll
    for (int q = 0; q < 8; ++q) {
      bf16x8 a;
      a[0]=(__bf16)xp0[q].x; a[1]=(__bf16)xp0[q].y;
      a[2]=(__bf16)xp0[q].z; a[3]=(__bf16)xp0[q].w;
      a[4]=(__bf16)xp1[q].x; a[5]=(__bf16)xp1[q].y;
      a[6]=(__bf16)xp1[q].z; a[7]=(__bf16)xp1[q].w;
#pragma unroll
      for (int nt = 0; nt < 4; ++nt)
        accN[nt] = __builtin_amdgcn_mfma_f32_16x16x32_bf16(
                     a, bw[((16 + q) * 4 + nt) * 64 + ln], accN[nt], 0, 0, 0);
    }
  };

  // one timestep: consumes acc (pre-seeded with x-part of t); after
  // publishing h_{t+1}, computes accN = x-part of t+1 and prefetches x(t+2)
  auto step = [&](f32x4 (&acc)[4], f32x4 (&accN)[4], int t) {
    if (t > 0) {
      // spin until all 32 col-groups published h_t (sc1 flag line)
      unsigned fv;
      do {
        asm volatile("global_load_dword %0, %1, off sc0 sc1\n\t"
                     "s_waitcnt vmcnt(0)"
                     : "=v"(fv) : "v"(fspin) : "memory");
      } while (__any((int)(fv < (unsigned)t)));

      bf16x8 hf[16];
      if constexpr (FAST) {
        // fresh address => plain cached loads are coherent (L2-shareable)
        const bf16x8* hrow = (const bf16x8*)(hbase + (size_t)(t - 1) * BH
                                             + (size_t)rowA * H_SZ) + lhi;
#pragma unroll
        for (int kt = 0; kt < 16; ++kt) hf[kt] = hrow[kt * 4];
      } else {
        const __bf16* hsrc = hbase + (size_t)(t & 1) * BH
                                   + (size_t)rowA * H_SZ + lhi * 8;
        HLOAD(hf[0],  "0");   HLOAD(hf[1],  "64");  HLOAD(hf[2],  "128");
        HLOAD(hf[3],  "192"); HLOAD(hf[4],  "256"); HLOAD(hf[5],  "320");
        HLOAD(hf[6],  "384"); HLOAD(hf[7],  "448"); HLOAD(hf[8],  "512");
        HLOAD(hf[9],  "576"); HLOAD(hf[10], "640"); HLOAD(hf[11], "704");
        HLOAD(hf[12], "768"); HLOAD(hf[13], "832"); HLOAD(hf[14], "896");
        HLOAD(hf[15], "960");
        asm volatile("s_waitcnt vmcnt(0)" ::: "memory");
        __builtin_amdgcn_sched_barrier(0);
      }
#pragma unroll
      for (int kt = 0; kt < 16; ++kt) {
#pragma unroll
        for (int nt = 0; nt < 4; ++nt)
          acc[nt] = __builtin_amdgcn_mfma_f32_16x16x32_bf16(
                      hf[kt], bw[(kt * 4 + nt) * 64 + ln], acc[nt], 0, 0, 0);
      }
    }

    // elementwise LSTM: acc[0..3][r] = f/i/o/chat for the SAME (row,col)
    float hnv[4];
#pragma unroll
    for (int r = 0; r < 4; ++r) {
      const float fg = fast_sigmoid(acc[0][r] + bias0);
      const float ig = fast_sigmoid(acc[1][r] + bias1);
      const float og = fast_sigmoid(acc[2][r] + bias2);
      const float gg = fast_tanh(acc[3][r] + bias3);
      const float cn = fg * cst[r] + ig * gg;
      cst[r] = cn;
      hnv[r] = og * fast_tanh(cn);
    }

    if (t < T_SZ - 1) {
      // publish h_{t+1} (write-through to L3), then set flag word (no RMW)
      __bf16* hdst = (FAST ? hbase + (size_t)t * BH
                           : hbase + (size_t)((t + 1) & 1) * BH)
                     + (size_t)rowD * H_SZ + colW;
      const unsigned u0 = __builtin_bit_cast(unsigned short, (__bf16)hnv[0]);
      const unsigned u1 = __builtin_bit_cast(unsigned short, (__bf16)hnv[1]);
      const unsigned u2 = __builtin_bit_cast(unsigned short, (__bf16)hnv[2]);
      const unsigned u3 = __builtin_bit_cast(unsigned short, (__bf16)hnv[3]);
      HSTORE("0",    u0);
      HSTORE("1024", u1);
      HSTORE("2048", u2);
      HSTORE("3072", u3);
      asm volatile("s_waitcnt vmcnt(0)" ::: "memory");  // h at L3
      if (ln == 0) {
        const unsigned tv = (unsigned)(t + 1);
        asm volatile("global_store_dword %0, %1, off sc0 sc1"
                     :: "v"(fq), "v"(tv) : "memory");
      }
      // x-part for t+1 (off the h critical path), then prefetch x(t+2)
      xpart(accN);
      xprefetch(t + 2);
    } else {
      // final h -> f32 for the fc head (plain stores; kernel-end release)
#pragma unroll
      for (int r = 0; r < 4; ++r)
        hf32[(size_t)(rowD + r) * H_SZ + colW] = hnv[r];
    }
  };

  f32x4 accA[4], accB[4];
  xprefetch(0);
  xpart(accA);                       // seed t=0 (h0 = 0 => no h-part)
  xprefetch(1);
  for (int t2 = 0; t2 < T_SZ; t2 += 2) {
    step(accA, accB, t2);
    step(accB, accA, t2 + 1);
  }
}

// out[b] = dot(h_T[b], fc_w) + fc_b
__global__ __launch_bounds__(256)
void fc_head(const float* __restrict__ hf32, const float* __restrict__ fcw,
             const float* __restrict__ fcb, float* __restrict__ out)
{
  const int b = blockIdx.x * 256 + threadIdx.x;
  if (b >= B_SZ) return;
  const float4* hp = (const float4*)(hf32 + (size_t)b * H_SZ);
  const float4* wp = (const float4*)fcw;
  float s = 0.f;
#pragma unroll 8
  for (int j = 0; j < H_SZ / 4; ++j) {
    const float4 h = hp[j];
    const float4 w = wp[j];
    s += h.x * w.x + h.y * w.y + h.z * w.z + h.w * w.w;
  }
  out[b] = s + fcb[0];
}

extern "C" void kernel_launch(void* const* d_in, const int* in_sizes, int n_in,
                              void* d_out, int out_size, void* d_ws, size_t ws_size,
                              hipStream_t stream) {
  const float* x   = (const float*)d_in[0];  // (B, T, I) f32
  const float* Ww  = (const float*)d_in[1];  // (2048, 768) f32
  const float* Wb  = (const float*)d_in[2];  // (2048,) f32
  const float* fcw = (const float*)d_in[3];  // (1, 512) f32
  const float* fcb = (const float*)d_in[4];  // (1,) f32
  float* out = (float*)d_out;                // (B, 1) f32

  char* ws = (char*)d_ws;
  unsigned int* flags = (unsigned int*)ws;

  // FAST layout: [flags 4K][hbufs 255*512K][hf32 1M]
  const size_t hbytes = (size_t)(T_SZ - 1) * BH * sizeof(__bf16);
  const size_t need   = 4096 + hbytes + (size_t)BH * sizeof(float);
  const bool fast = (ws_size >= need);

  hipMemsetAsync(ws, 0, 4096, stream);  // flags only; h never read pre-write

  if (fast) {
    __bf16* hbase = (__bf16*)(ws + 4096);
    float*  hf32  = (float*)(ws + 4096 + hbytes);
    lstm_persist<true><<<256, 256, 0, stream>>>(x, Ww, Wb, hbase, hf32, flags);
    fc_head<<<2, 256, 0, stream>>>(hf32, fcw, fcb, out);
  } else {
    __bf16* hbase = (__bf16*)(ws + 4096);
    float*  hf32  = (float*)(ws + 4096 + (size_t)2 * BH * sizeof(__bf16));
    lstm_persist<false><<<256, 256, 0, stream>>>(x, Ww, Wb, hbase, hf32, flags);
    fc_head<<<2, 256, 0, stream>>>(hf32, fcw, fcb, out);
  }
}